// Round 1
// 672.053 us; speedup vs baseline: 1.0612x; 1.0612x over previous
//
#include <hip/hip_runtime.h>

// ---------------------------------------------------------------------------
// ScaledDotProductAttention: B=8, Sq=Sk=2048, D=E=1024, f32 in/out.
// Round 3: all-bf16 dataflow. Lt/rnn pre-converted to bf16; softmax emits a
// bf16 P copy. Every GEMM now takes the pure global_load_lds staging path
// (no f32 reg-staging / cvt in any GEMM inner loop). Numerics identical to
// the previous round (bf16 rounding happened during staging anyway).
// ---------------------------------------------------------------------------

typedef __bf16 bf16x8 __attribute__((ext_vector_type(8)));
typedef __bf16 bf16x4 __attribute__((ext_vector_type(4)));
typedef float  f32x4  __attribute__((ext_vector_type(4)));

__device__ __forceinline__ void gload_lds16(const void* g, void* l) {
  __builtin_amdgcn_global_load_lds(
      (__attribute__((address_space(1))) void*)(g),
      (__attribute__((address_space(3))) void*)(uintptr_t)(l),
      16, 0, 0);
}

// LDS tile: 128 rows x 64 bf16 cols = 128B rows = 8 granules of 16B.
// Granule g of row r lives at position g ^ (r & 7)  -> bank-conflict-free
// for both row-wise staging and 16-consecutive-row fragment reads.
__device__ __forceinline__ int swz(int r, int g) {
  return r * 64 + ((g ^ (r & 7)) << 3);
}

// ---------------------------------------------------------------------------
// NT GEMM, pure bf16 operands: C[m,n] = sum_k A[m,k]*B[n,k].
// M,N mult of 128, K mult of 64. 256 threads = 4 waves (2x2), wave does
// 64x64 via 4x4 MFMA 16x16x32, two k-half passes per BK=64 tile.
// ---------------------------------------------------------------------------
template <bool OUTBF16>
__global__ __launch_bounds__(256)
void gemm_nt(const __bf16* __restrict__ Ap, const __bf16* __restrict__ Bp,
             void* __restrict__ Cp, int N, int K,
             unsigned long long sAb, unsigned long long sBb,
             unsigned long long sCb, float scale) {
  __shared__ __bf16 As[128 * 64];
  __shared__ __bf16 Bs[128 * 64];

  const int tid  = threadIdx.x;
  const int wave = tid >> 6;
  const int lane = tid & 63;
  const int wm   = (wave >> 1) * 64;
  const int wn   = (wave & 1) * 64;

  // ---- XCD/L2-aware block swizzle ----
  int bx, by, bz;
  {
    const int nx = gridDim.x, ny = gridDim.y;
    const int d = blockIdx.x + nx * (blockIdx.y + ny * blockIdx.z);
    if (gridDim.z == 8 && ((nx * ny) & 63) == 0 && (nx & 7) == 0) {
      bz = d & 7;                       // one batch per XCD (heuristic)
      const int s = d >> 3;
      const int sq = s >> 6, w = s & 63;  // 8x8 squares within the batch grid
      const int nsx = nx >> 3;
      const int sqx = sq % nsx, sqy = sq / nsx;
      bx = sqx * 8 + (w & 7);
      by = sqy * 8 + (w >> 3);
    } else {
      bx = blockIdx.x; by = blockIdx.y; bz = blockIdx.z;
    }
  }
  const size_t m0 = (size_t)by * 128;
  const size_t n0 = (size_t)bx * 128;
  const __bf16* Ab = Ap + (size_t)bz * sAb;
  const __bf16* Bb = Bp + (size_t)bz * sBb;

  f32x4 acc[4][4] = {};
  const int fm = lane & 15;

  for (int kt = 0; kt < K; kt += 64) {
    // ---- stage A tile (128 x 64 bf16), source pre-swizzled, LDS linear ----
#pragma unroll
    for (int i = 0; i < 4; ++i) {
      const int c = wave * 4 + i;        // 8-row chunk (1 KB LDS)
      const int r = c * 8 + (lane >> 3);
      const int g = (lane & 7) ^ (r & 7);
      gload_lds16(Ab + (m0 + r) * (size_t)K + kt + g * 8, &As[c * 512]);
    }
    // ---- stage B tile (128 x 64 bf16) ----
#pragma unroll
    for (int i = 0; i < 4; ++i) {
      const int c = wave * 4 + i;
      const int r = c * 8 + (lane >> 3);
      const int g = (lane & 7) ^ (r & 7);
      gload_lds16(Bb + (n0 + r) * (size_t)K + kt + g * 8, &Bs[c * 512]);
    }
    __syncthreads();

    // ---- MFMA: two k-half passes (k32 each) ----
#pragma unroll
    for (int h = 0; h < 2; ++h) {
      const int gq = (lane >> 4) + h * 4;  // 16B granule index of this lane's k8
      bf16x8 afr[4], bfr[4];
#pragma unroll
      for (int i = 0; i < 4; ++i)
        afr[i] = *(const bf16x8*)&As[swz(wm + i * 16 + fm, gq)];
#pragma unroll
      for (int j = 0; j < 4; ++j)
        bfr[j] = *(const bf16x8*)&Bs[swz(wn + j * 16 + fm, gq)];
#pragma unroll
      for (int i = 0; i < 4; ++i)
#pragma unroll
        for (int j = 0; j < 4; ++j)
          acc[i][j] = __builtin_amdgcn_mfma_f32_16x16x32_bf16(
              afr[i], bfr[j], acc[i][j], 0, 0, 0);
    }
    __syncthreads();
  }

  // ---- epilogue: C/D layout col=lane&15, row=(lane>>4)*4+reg ----
  const int col   = lane & 15;
  const int rquad = (lane >> 4) * 4;
#pragma unroll
  for (int i = 0; i < 4; ++i) {
#pragma unroll
    for (int r = 0; r < 4; ++r) {
      const size_t row = m0 + wm + i * 16 + rquad + r;
#pragma unroll
      for (int j = 0; j < 4; ++j) {
        const size_t cidx = (size_t)bz * sCb + row * (size_t)N + n0 + wn + j * 16 + col;
        if constexpr (OUTBF16) {
          ((__bf16*)Cp)[cidx] = (__bf16)acc[i][j][r];
        } else {
          ((float*)Cp)[cidx] = acc[i][j][r] * scale;
        }
      }
    }
  }
}

// ---------------------------------------------------------------------------
// cvt+transpose 1024x1024 f32 -> bf16 (out[n,d] = in[d,n]); z selects matrix
// ---------------------------------------------------------------------------
__global__ __launch_bounds__(256)
void cvt_transpose(const float* __restrict__ s0, const float* __restrict__ s1,
                   const float* __restrict__ s2, __bf16* __restrict__ d0,
                   __bf16* __restrict__ d1, __bf16* __restrict__ d2) {
  const float* s = blockIdx.z == 0 ? s0 : (blockIdx.z == 1 ? s1 : s2);
  __bf16* d      = blockIdx.z == 0 ? d0 : (blockIdx.z == 1 ? d1 : d2);
  __shared__ float tile[32][33];
  const int x  = blockIdx.x * 32 + threadIdx.x;
  const int y0 = blockIdx.y * 32;
  for (int j = threadIdx.y; j < 32; j += 8)
    tile[j][threadIdx.x] = s[(size_t)(y0 + j) * 1024 + x];
  __syncthreads();
  const int x2 = y0 + threadIdx.x;
  const int y2 = blockIdx.x * 32;
  for (int j = threadIdx.y; j < 32; j += 8)
    d[(size_t)(y2 + j) * 1024 + x2] = (__bf16)tile[threadIdx.x][j];
}

// ---------------------------------------------------------------------------
// elementwise f32 -> bf16, 16777216 elems per z-slice (Lt and rnn_ht)
// ---------------------------------------------------------------------------
__global__ __launch_bounds__(256)
void cvt_bf16(const float* __restrict__ s0, __bf16* __restrict__ d0,
              const float* __restrict__ s1, __bf16* __restrict__ d1) {
  const float* s = blockIdx.z ? s1 : s0;
  __bf16* d      = blockIdx.z ? d1 : d0;
  const size_t i = ((size_t)blockIdx.x * 256 + threadIdx.x) * 4;
  float4 f = *(const float4*)(s + i);
  bf16x4 h = {(__bf16)f.x, (__bf16)f.y, (__bf16)f.z, (__bf16)f.w};
  *(bf16x4*)(d + i) = h;
}

// ---------------------------------------------------------------------------
// row softmax in place: 16384 rows x 2048 f32, one block per row.
// Also emits a bf16 copy of the row (PV GEMM A-operand).
// ---------------------------------------------------------------------------
__global__ __launch_bounds__(256)
void softmax_rows(float* __restrict__ Wt, __bf16* __restrict__ Pb) {
  const int t = threadIdx.x;
  float* p = Wt + (size_t)blockIdx.x * 2048;
  float4 a = ((float4*)p)[t];
  float4 b = ((float4*)p)[t + 256];

  float m = fmaxf(fmaxf(fmaxf(a.x, a.y), fmaxf(a.z, a.w)),
                  fmaxf(fmaxf(b.x, b.y), fmaxf(b.z, b.w)));
#pragma unroll
  for (int off = 32; off > 0; off >>= 1) m = fmaxf(m, __shfl_xor(m, off));
  __shared__ float red[8];
  if ((t & 63) == 0) red[t >> 6] = m;
  __syncthreads();
  m = fmaxf(fmaxf(red[0], red[1]), fmaxf(red[2], red[3]));

  a.x = __expf(a.x - m); a.y = __expf(a.y - m);
  a.z = __expf(a.z - m); a.w = __expf(a.w - m);
  b.x = __expf(b.x - m); b.y = __expf(b.y - m);
  b.z = __expf(b.z - m); b.w = __expf(b.w - m);
  float s = a.x + a.y + a.z + a.w + b.x + b.y + b.z + b.w;
#pragma unroll
  for (int off = 32; off > 0; off >>= 1) s += __shfl_xor(s, off);
  if ((t & 63) == 0) red[4 + (t >> 6)] = s;
  __syncthreads();
  s = red[4] + red[5] + red[6] + red[7];

  const float inv = 1.0f / s;
  a.x *= inv; a.y *= inv; a.z *= inv; a.w *= inv;
  b.x *= inv; b.y *= inv; b.z *= inv; b.w *= inv;
  ((float4*)p)[t] = a;
  ((float4*)p)[t + 256] = b;

  __bf16* pb = Pb + (size_t)blockIdx.x * 2048;
  bf16x4 ha = {(__bf16)a.x, (__bf16)a.y, (__bf16)a.z, (__bf16)a.w};
  bf16x4 hb = {(__bf16)b.x, (__bf16)b.y, (__bf16)b.z, (__bf16)b.w};
  *(bf16x4*)(pb + (size_t)t * 4) = ha;
  *(bf16x4*)(pb + (size_t)(t + 256) * 4) = hb;
}

// ---------------------------------------------------------------------------
extern "C" void kernel_launch(void* const* d_in, const int* in_sizes, int n_in,
                              void* d_out, int out_size, void* d_ws,
                              size_t ws_size, hipStream_t stream) {
  const float* Lt  = (const float*)d_in[0];  // [8,2048,1024]
  const float* rnn = (const float*)d_in[1];  // [8,2048,1024]
  const float* ker = (const float*)d_in[2];  // [2,1024,1024]
  const float* W   = (const float*)d_in[3];  // [1024,1024]

  float* ctx = (float*)d_out;                // [8,2048,1024]
  float* wts = ctx + (size_t)16777216;       // [8,2048,2048]

  __bf16* ws   = (__bf16*)d_ws;
  __bf16* Wt   = ws;                         // [1024,1024]  (n,d)   2 MiB
  __bf16* k0t  = Wt + (1u << 20);            // [1024,1024]          2 MiB
  __bf16* k1t  = k0t + (1u << 20);           // [1024,1024]          2 MiB
  __bf16* WQ   = k1t + (1u << 20);           // [8*2048,1024]       32 MiB
  __bf16* WK   = WQ + (16u << 20);           // [8*2048,1024]       32 MiB
  __bf16* WVt  = WK + (16u << 20);           // [8][1024][2048]     32 MiB
  __bf16* Ltb  = WVt + (16u << 20);          // [8,2048,1024] bf16  32 MiB
  __bf16* rnnb = Ltb + (16u << 20);          // [8,2048,1024] bf16  32 MiB
  // Pb overlaps Ltb+rnnb (both dead once softmax runs): [8,2048,2048] bf16
  __bf16* Pb = Ltb;                          //                     64 MiB

  // 1) transpose + cvt the three weight matrices
  cvt_transpose<<<dim3(32, 32, 3), dim3(32, 8), 0, stream>>>(
      W, ker, ker + (1u << 20), Wt, k0t, k1t);

  // 1b) cvt Lt and rnn_ht to bf16 (rounding identical to old in-GEMM cvt)
  cvt_bf16<<<dim3(16384, 1, 2), 256, 0, stream>>>(Lt, Ltb, rnn, rnnb);

  // 2) projections (NT): WQ = rnn @ Wt, WK = Lt @ k0t
  gemm_nt<true><<<dim3(8, 128, 1), 256, 0, stream>>>(
      rnnb, Wt, WQ, 1024, 1024, 0ull, 0ull, 0ull, 1.0f);
  gemm_nt<true><<<dim3(8, 128, 1), 256, 0, stream>>>(
      Ltb, k0t, WK, 1024, 1024, 0ull, 0ull, 0ull, 1.0f);

  // 3) WVt[b][e][k] = sum_d k1t[e,d] * Lt[b,k,d]  (NT, batched B)
  gemm_nt<true><<<dim3(16, 8, 8), 256, 0, stream>>>(
      k1t, Ltb, WVt, 2048, 1024, 0ull, 2048ull * 1024ull,
      1024ull * 2048ull, 1.0f);

  // 4) QK logits, *0.125, f32 -> weights region of d_out
  gemm_nt<false><<<dim3(16, 16, 8), 256, 0, stream>>>(
      WQ, WK, wts, 2048, 1024, 2048ull * 1024ull, 2048ull * 1024ull,
      2048ull * 2048ull, 0.125f);

  // 5) softmax rows in place (+ bf16 copy for PV)
  softmax_rows<<<16384, 256, 0, stream>>>(wts, Pb);

  // 6) ctx[b,q,e] = sum_k P[b,q,k] * WVt[b,e,k]  (pure bf16)
  gemm_nt<false><<<dim3(8, 16, 8), 256, 0, stream>>>(
      Pb, WVt, ctx, 1024, 2048, 2048ull * 2048ull, 1024ull * 2048ull,
      2048ull * 1024ull, 1.0f);
}

// Round 2
// 584.448 us; speedup vs baseline: 1.2203x; 1.1499x over previous
//
#include <hip/hip_runtime.h>

// ---------------------------------------------------------------------------
// ScaledDotProductAttention: B=8, Sq=Sk=2048, D=E=1024, f32 in/out.
// Round 4: 256x256 8-phase GEMM (HK-style schedule in plain HIP).
//   BM=BN=256, BK=64, 512 thr = 8 waves (2M x 4N), wave tile 128x64.
//   LDS 128 KiB: 2 bufs x {A,B} x 2 K-halves x 16 KiB regions.
//   Per phase: ds_read one quadrant's frags (4/8 x b128) + stage exactly one
//   half-tile (2 x global_load_lds dwordx4) + raw s_barrier + setprio'd
//   16 MFMA + s_barrier.  Counted s_waitcnt vmcnt(6) only at phases 4 & 8
//   (3 half-tiles stay in flight across barriers; never drains to 0).
//   Stage targets always the region consumed in the previous phase:
//     ph1:(t+1).Akh1  ph2:(t+2).Bkh0  ph3:(t+2).Akh0  ph4:(t+2).Bkh1
//     ph5:(t+2).Akh1  ph6:(t+3).Bkh0  ph7:(t+3).Akh0  ph8:(t+3).Bkh1
//   XOR swizzle g^=((row>>1)&3) on 16B granules: 2-way bank spread on
//   ds_read_b128 (free), applied pre-swizzled on the global source so the
//   linear global_load_lds destination stays legal (both-sides rule).
// ---------------------------------------------------------------------------

typedef __bf16 bf16x8 __attribute__((ext_vector_type(8)));
typedef __bf16 bf16x4 __attribute__((ext_vector_type(4)));
typedef float  f32x4  __attribute__((ext_vector_type(4)));

__device__ __forceinline__ void gload_lds16(const void* g, void* l) {
  __builtin_amdgcn_global_load_lds(
      (__attribute__((address_space(1))) void*)(g),
      (__attribute__((address_space(3))) void*)(uintptr_t)(l),
      16, 0, 0);
}

// Read 4 MFMA A/B fragments (16x16x32) from a 256x32 K-half region.
// Region layout: elem = row*32 + granule*8, granule pre-swizzled by
// g ^ ((row>>1)&3).
__device__ __forceinline__ void ldfrag4(bf16x8 (&f)[4], const __bf16* reg_,
                                        int rbase, int fm, int gq) {
#pragma unroll
  for (int i = 0; i < 4; ++i) {
    const int r = rbase + i * 16 + fm;
    f[i] = *(const bf16x8*)(reg_ + r * 32 + ((gq ^ ((r >> 1) & 3)) << 3));
  }
}

// Stage one 256x32 K-half (16 KiB) : 2 global_load_lds per thread.
// src must already point at (tile_row0, k_half_col0) of the operand.
__device__ __forceinline__ void stage16(const __bf16* src, __bf16* dst,
                                        size_t rowstride, int wave, int lane) {
#pragma unroll
  for (int i = 0; i < 2; ++i) {
    const int chunk = wave * 2 + i;            // 16 chunks of 16 rows
    const int row = chunk * 16 + (lane >> 2);
    const int gg = (lane & 3) ^ ((row >> 1) & 3);   // inverse (=same) swizzle
    gload_lds16(src + (size_t)row * rowstride + (gg << 3), dst + chunk * 512);
  }
}

template <int MH>
__device__ __forceinline__ void mfma16(f32x4 (&acc)[8][4], const bf16x8 (&a)[4],
                                       const bf16x8 (&b)[4]) {
#pragma unroll
  for (int mi = 0; mi < 4; ++mi)
#pragma unroll
    for (int nj = 0; nj < 4; ++nj)
      acc[MH * 4 + mi][nj] = __builtin_amdgcn_mfma_f32_16x16x32_bf16(
          a[mi], b[nj], acc[MH * 4 + mi][nj], 0, 0, 0);
}

#define PHASE_MID()                       \
  __builtin_amdgcn_sched_barrier(0);      \
  __builtin_amdgcn_s_barrier();           \
  __builtin_amdgcn_s_setprio(1)

#define PHASE_END()                       \
  __builtin_amdgcn_s_setprio(0);          \
  __builtin_amdgcn_sched_barrier(0);      \
  __builtin_amdgcn_s_barrier()

// ---------------------------------------------------------------------------
// NT GEMM, bf16 operands: C[m,n] = sum_k A[m,k]*B[n,k].
// M,N mult of 256, K mult of 128.
// ---------------------------------------------------------------------------
template <bool OUTBF16>
__global__ __launch_bounds__(512, 2)
void gemm_nt(const __bf16* __restrict__ Ap, const __bf16* __restrict__ Bp,
             void* __restrict__ Cp, int N, int K,
             unsigned long long sAb, unsigned long long sBb,
             unsigned long long sCb, float scale) {
  __shared__ __bf16 lds[65536];  // 128 KiB

  const int tid  = threadIdx.x;
  const int wave = tid >> 6;
  const int lane = tid & 63;
  const int wm   = (wave >> 2) * 128;   // 2 wave-rows
  const int wn   = (wave & 3) * 64;     // 4 wave-cols
  const int fm   = lane & 15;
  const int gq   = lane >> 4;           // k8-granule within a K-half

  // ---- XCD/L2-aware block swizzle (bijective) ----
  int bx, by, bz;
  {
    const int nx = gridDim.x, ny = gridDim.y;
    const int d = blockIdx.x + nx * (blockIdx.y + ny * blockIdx.z);
    if (gridDim.z == 8) {
      bz = d & 7;                 // one batch per XCD
      const int s = d >> 3;
      bx = s % nx; by = s / nx;
    } else {
      const int cpx = (nx * ny) >> 3;
      const int s = (d & 7) * cpx + (d >> 3);
      bx = s % nx; by = s / nx; bz = 0;
    }
  }
  const size_t m0 = (size_t)by * 256;
  const size_t n0 = (size_t)bx * 256;
  const __bf16* Aa = Ap + (size_t)bz * sAb + m0 * (size_t)K;
  const __bf16* Ba = Bp + (size_t)bz * sBb + n0 * (size_t)K;

  // LDS regions: A[buf][kh] then B[buf][kh], each 8192 bf16 (16 KiB)
  __bf16* const As_ = lds;
  __bf16* const Bs_ = lds + 32768;
#define AREG(p, h) (As_ + (p) * 16384 + (h) * 8192)
#define BREG(p, h) (Bs_ + (p) * 16384 + (h) * 8192)

  f32x4 acc[8][4] = {};
  bf16x8 a[4], b[4];

  // ---- prologue: tile0 fully + 3 halves of tile1 ----
  stage16(Ba + 0,  BREG(0, 0), K, wave, lane);
  stage16(Aa + 0,  AREG(0, 0), K, wave, lane);
  stage16(Ba + 32, BREG(0, 1), K, wave, lane);
  stage16(Aa + 32, AREG(0, 1), K, wave, lane);
  asm volatile("s_waitcnt vmcnt(4)" ::: "memory");
  stage16(Ba + 64, BREG(1, 0), K, wave, lane);
  stage16(Aa + 64, AREG(1, 0), K, wave, lane);
  stage16(Ba + 96, BREG(1, 1), K, wave, lane);
  asm volatile("s_waitcnt vmcnt(6)" ::: "memory");
  __builtin_amdgcn_s_barrier();

  const int niter = K >> 7;   // 2 K-tiles (BK=64) per iteration
  for (int it = 0; it < niter; ++it) {
    const int kt = it << 7;
    const bool s2 = (kt + 128) < K;   // tiles t+2 / t+3 exist

    // ---- phase 1: buf0 (mh0,kh0); stage (t+1).A-kh1 ----
    ldfrag4(a, AREG(0, 0), wm, fm, gq);
    ldfrag4(b, BREG(0, 0), wn, fm, gq);
    stage16(Aa + kt + 96, AREG(1, 1), K, wave, lane);
    PHASE_MID();
    mfma16<0>(acc, a, b);
    PHASE_END();

    // ---- phase 2: (mh1,kh0); stage (t+2).B-kh0 ----
    ldfrag4(a, AREG(0, 0), wm + 64, fm, gq);
    if (s2) stage16(Ba + kt + 128, BREG(0, 0), K, wave, lane);
    PHASE_MID();
    mfma16<1>(acc, a, b);
    PHASE_END();

    // ---- phase 3: (mh0,kh1); stage (t+2).A-kh0 ----
    ldfrag4(a, AREG(0, 1), wm, fm, gq);
    ldfrag4(b, BREG(0, 1), wn, fm, gq);
    if (s2) stage16(Aa + kt + 128, AREG(0, 0), K, wave, lane);
    PHASE_MID();
    mfma16<0>(acc, a, b);
    PHASE_END();

    // ---- phase 4: (mh1,kh1); stage (t+2).B-kh1; counted vmcnt ----
    ldfrag4(a, AREG(0, 1), wm + 64, fm, gq);
    if (s2) stage16(Ba + kt + 160, BREG(0, 1), K, wave, lane);
    PHASE_MID();
    mfma16<1>(acc, a, b);
    __builtin_amdgcn_s_setprio(0);
    __builtin_amdgcn_sched_barrier(0);
    if (s2) { asm volatile("s_waitcnt vmcnt(6)" ::: "memory"); }
    else    { asm volatile("s_waitcnt vmcnt(0)" ::: "memory"); }
    __builtin_amdgcn_s_barrier();

    // ---- phase 5: buf1 (mh0,kh0); stage (t+2).A-kh1 ----
    ldfrag4(a, AREG(1, 0), wm, fm, gq);
    ldfrag4(b, BREG(1, 0), wn, fm, gq);
    if (s2) stage16(Aa + kt + 160, AREG(0, 1), K, wave, lane);
    PHASE_MID();
    mfma16<0>(acc, a, b);
    PHASE_END();

    // ---- phase 6: (mh1,kh0); stage (t+3).B-kh0 ----
    ldfrag4(a, AREG(1, 0), wm + 64, fm, gq);
    if (s2) stage16(Ba + kt + 192, BREG(1, 0), K, wave, lane);
    PHASE_MID();
    mfma16<1>(acc, a, b);
    PHASE_END();

    // ---- phase 7: (mh0,kh1); stage (t+3).A-kh0 ----
    ldfrag4(a, AREG(1, 1), wm, fm, gq);
    ldfrag4(b, BREG(1, 1), wn, fm, gq);
    if (s2) stage16(Aa + kt + 192, AREG(1, 0), K, wave, lane);
    PHASE_MID();
    mfma16<0>(acc, a, b);
    PHASE_END();

    // ---- phase 8: (mh1,kh1); stage (t+3).B-kh1; counted vmcnt ----
    ldfrag4(a, AREG(1, 1), wm + 64, fm, gq);
    if (s2) stage16(Ba + kt + 224, BREG(1, 1), K, wave, lane);
    PHASE_MID();
    mfma16<1>(acc, a, b);
    __builtin_amdgcn_s_setprio(0);
    __builtin_amdgcn_sched_barrier(0);
    if (s2) { asm volatile("s_waitcnt vmcnt(6)" ::: "memory"); }
    __builtin_amdgcn_s_barrier();
  }

  // ---- epilogue: C/D layout col=lane&15, row=(lane>>4)*4+reg ----
  const int col   = lane & 15;
  const int rquad = (lane >> 4) * 4;
#pragma unroll
  for (int mi = 0; mi < 8; ++mi) {
#pragma unroll
    for (int r = 0; r < 4; ++r) {
      const size_t row = m0 + wm + mi * 16 + rquad + r;
#pragma unroll
      for (int nj = 0; nj < 4; ++nj) {
        const size_t cidx =
            (size_t)bz * sCb + row * (size_t)N + n0 + wn + nj * 16 + col;
        if constexpr (OUTBF16) {
          ((__bf16*)Cp)[cidx] = (__bf16)acc[mi][nj][r];
        } else {
          ((float*)Cp)[cidx] = acc[mi][nj][r] * scale;
        }
      }
    }
  }
#undef AREG
#undef BREG
}

// ---------------------------------------------------------------------------
// cvt+transpose 1024x1024 f32 -> bf16 (out[n,d] = in[d,n]); z selects matrix
// ---------------------------------------------------------------------------
__global__ __launch_bounds__(256)
void cvt_transpose(const float* __restrict__ s0, const float* __restrict__ s1,
                   const float* __restrict__ s2, __bf16* __restrict__ d0,
                   __bf16* __restrict__ d1, __bf16* __restrict__ d2) {
  const float* s = blockIdx.z == 0 ? s0 : (blockIdx.z == 1 ? s1 : s2);
  __bf16* d      = blockIdx.z == 0 ? d0 : (blockIdx.z == 1 ? d1 : d2);
  __shared__ float tile[32][33];
  const int x  = blockIdx.x * 32 + threadIdx.x;
  const int y0 = blockIdx.y * 32;
  for (int j = threadIdx.y; j < 32; j += 8)
    tile[j][threadIdx.x] = s[(size_t)(y0 + j) * 1024 + x];
  __syncthreads();
  const int x2 = y0 + threadIdx.x;
  const int y2 = blockIdx.x * 32;
  for (int j = threadIdx.y; j < 32; j += 8)
    d[(size_t)(y2 + j) * 1024 + x2] = (__bf16)tile[threadIdx.x][j];
}

// ---------------------------------------------------------------------------
// elementwise f32 -> bf16, Lt and rnn_ht
// ---------------------------------------------------------------------------
__global__ __launch_bounds__(256)
void cvt_bf16(const float* __restrict__ s0, __bf16* __restrict__ d0,
              const float* __restrict__ s1, __bf16* __restrict__ d1) {
  const float* s = blockIdx.z ? s1 : s0;
  __bf16* d      = blockIdx.z ? d1 : d0;
  const size_t i = ((size_t)blockIdx.x * 256 + threadIdx.x) * 4;
  float4 f = *(const float4*)(s + i);
  bf16x4 h = {(__bf16)f.x, (__bf16)f.y, (__bf16)f.z, (__bf16)f.w};
  *(bf16x4*)(d + i) = h;
}

// ---------------------------------------------------------------------------
// row softmax in place: 16384 rows x 2048 f32, one block per row.
// Also emits a bf16 copy of the row (PV GEMM A-operand).
// ---------------------------------------------------------------------------
__global__ __launch_bounds__(256)
void softmax_rows(float* __restrict__ Wt, __bf16* __restrict__ Pb) {
  const int t = threadIdx.x;
  float* p = Wt + (size_t)blockIdx.x * 2048;
  float4 a = ((float4*)p)[t];
  float4 b = ((float4*)p)[t + 256];

  float m = fmaxf(fmaxf(fmaxf(a.x, a.y), fmaxf(a.z, a.w)),
                  fmaxf(fmaxf(b.x, b.y), fmaxf(b.z, b.w)));
#pragma unroll
  for (int off = 32; off > 0; off >>= 1) m = fmaxf(m, __shfl_xor(m, off));
  __shared__ float red[8];
  if ((t & 63) == 0) red[t >> 6] = m;
  __syncthreads();
  m = fmaxf(fmaxf(red[0], red[1]), fmaxf(red[2], red[3]));

  a.x = __expf(a.x - m); a.y = __expf(a.y - m);
  a.z = __expf(a.z - m); a.w = __expf(a.w - m);
  b.x = __expf(b.x - m); b.y = __expf(b.y - m);
  b.z = __expf(b.z - m); b.w = __expf(b.w - m);
  float s = a.x + a.y + a.z + a.w + b.x + b.y + b.z + b.w;
#pragma unroll
  for (int off = 32; off > 0; off >>= 1) s += __shfl_xor(s, off);
  if ((t & 63) == 0) red[4 + (t >> 6)] = s;
  __syncthreads();
  s = red[4] + red[5] + red[6] + red[7];

  const float inv = 1.0f / s;
  a.x *= inv; a.y *= inv; a.z *= inv; a.w *= inv;
  b.x *= inv; b.y *= inv; b.z *= inv; b.w *= inv;
  ((float4*)p)[t] = a;
  ((float4*)p)[t + 256] = b;

  __bf16* pb = Pb + (size_t)blockIdx.x * 2048;
  bf16x4 ha = {(__bf16)a.x, (__bf16)a.y, (__bf16)a.z, (__bf16)a.w};
  bf16x4 hb = {(__bf16)b.x, (__bf16)b.y, (__bf16)b.z, (__bf16)b.w};
  *(bf16x4*)(pb + (size_t)t * 4) = ha;
  *(bf16x4*)(pb + (size_t)(t + 256) * 4) = hb;
}

// ---------------------------------------------------------------------------
extern "C" void kernel_launch(void* const* d_in, const int* in_sizes, int n_in,
                              void* d_out, int out_size, void* d_ws,
                              size_t ws_size, hipStream_t stream) {
  const float* Lt  = (const float*)d_in[0];  // [8,2048,1024]
  const float* rnn = (const float*)d_in[1];  // [8,2048,1024]
  const float* ker = (const float*)d_in[2];  // [2,1024,1024]
  const float* W   = (const float*)d_in[3];  // [1024,1024]

  float* ctx = (float*)d_out;                // [8,2048,1024]
  float* wts = ctx + (size_t)16777216;       // [8,2048,2048]

  __bf16* ws   = (__bf16*)d_ws;
  __bf16* Wt   = ws;                         // [1024,1024]  (n,d)   2 MiB
  __bf16* k0t  = Wt + (1u << 20);            // [1024,1024]          2 MiB
  __bf16* k1t  = k0t + (1u << 20);           // [1024,1024]          2 MiB
  __bf16* WQ   = k1t + (1u << 20);           // [8*2048,1024]       32 MiB
  __bf16* WK   = WQ + (16u << 20);           // [8*2048,1024]       32 MiB
  __bf16* WVt  = WK + (16u << 20);           // [8][1024][2048]     32 MiB
  __bf16* Ltb  = WVt + (16u << 20);          // [8,2048,1024] bf16  32 MiB
  __bf16* rnnb = Ltb + (16u << 20);          // [8,2048,1024] bf16  32 MiB
  __bf16* Pb = Ltb;  // P overlaps Ltb+rnnb (dead after WV/QK)      64 MiB

  // 1) transpose + cvt the three weight matrices
  cvt_transpose<<<dim3(32, 32, 3), dim3(32, 8), 0, stream>>>(
      W, ker, ker + (1u << 20), Wt, k0t, k1t);

  // 1b) cvt Lt and rnn_ht to bf16
  cvt_bf16<<<dim3(16384, 1, 2), 256, 0, stream>>>(Lt, Ltb, rnn, rnnb);

  // 2) projections (NT): WQ = rnn @ Wt, WK = Lt @ k0t
  gemm_nt<true><<<dim3(4, 64, 1), 512, 0, stream>>>(
      rnnb, Wt, WQ, 1024, 1024, 0ull, 0ull, 0ull, 1.0f);
  gemm_nt<true><<<dim3(4, 64, 1), 512, 0, stream>>>(
      Ltb, k0t, WK, 1024, 1024, 0ull, 0ull, 0ull, 1.0f);

  // 3) WVt[b][e][k] = sum_d k1t[e,d] * Lt[b,k,d]  (NT, batched B)
  gemm_nt<true><<<dim3(8, 4, 8), 512, 0, stream>>>(
      k1t, Ltb, WVt, 2048, 1024, 0ull, 2048ull * 1024ull,
      1024ull * 2048ull, 1.0f);

  // 4) QK logits, *0.125, f32 -> weights region of d_out
  gemm_nt<false><<<dim3(8, 8, 8), 512, 0, stream>>>(
      WQ, WK, wts, 2048, 1024, 2048ull * 1024ull, 2048ull * 1024ull,
      2048ull * 2048ull, 0.125f);

  // 5) softmax rows in place (+ bf16 copy for PV)
  softmax_rows<<<16384, 256, 0, stream>>>(wts, Pb);

  // 6) ctx[b,q,e] = sum_k P[b,q,k] * WVt[b,e,k]  (pure bf16)
  gemm_nt<false><<<dim3(4, 8, 8), 512, 0, stream>>>(
      Pb, WVt, ctx, 1024, 2048, 2048ull * 2048ull, 1024ull * 2048ull,
      2048ull * 1024ull, 1.0f);
}

// Round 4
// 555.939 us; speedup vs baseline: 1.2829x; 1.0513x over previous
//
#include <hip/hip_runtime.h>

// ---------------------------------------------------------------------------
// ScaledDotProductAttention: B=8, Sq=Sk=2048, D=E=1024, f32 in/out.
// Round 6 (= round 5 resubmit after infra failure; barrier-uniformity and
// bounds re-audited): persistent-block tile chaining on the 256x256 8-phase
// GEMM.
//   - proj1+proj2+WV merged into ONE launch: 256 blocks x 3 chained tiles.
//   - QK: 256 blocks x 2 chained tiles (B-panel reused L2-hot).
//   - Chain boundary: next tile's prologue loads issue right after the
//     epilogue stores; FIFO vmcnt makes the prologue wait cover the store
//     drain (max instead of sum). Steady-state loop identical to round 4.
// ---------------------------------------------------------------------------

typedef __bf16 bf16x8 __attribute__((ext_vector_type(8)));
typedef __bf16 bf16x4 __attribute__((ext_vector_type(4)));
typedef float  f32x4  __attribute__((ext_vector_type(4)));

__device__ __forceinline__ void gload_lds16(const void* g, void* l) {
  __builtin_amdgcn_global_load_lds(
      (__attribute__((address_space(1))) void*)(g),
      (__attribute__((address_space(3))) void*)(uintptr_t)(l),
      16, 0, 0);
}

// Read 4 MFMA A/B fragments (16x16x32) from a 256x32 K-half region.
// Region layout: elem = row*32 + granule*8, granule pre-swizzled by
// g ^ ((row>>1)&3).
__device__ __forceinline__ void ldfrag4(bf16x8 (&f)[4], const __bf16* reg_,
                                        int rbase, int fm, int gq) {
#pragma unroll
  for (int i = 0; i < 4; ++i) {
    const int r = rbase + i * 16 + fm;
    f[i] = *(const bf16x8*)(reg_ + r * 32 + ((gq ^ ((r >> 1) & 3)) << 3));
  }
}

// Stage one 256x32 K-half (16 KiB): 2 global_load_lds per thread.
// src points at (tile_row0, k_half_col0); rows stride `rowstride` elems.
// Each wave fills only its own chunks; the phase-4/8 counted vmcnt + barrier
// publishes all chunks block-wide before any cross-wave read.
__device__ __forceinline__ void stage16(const __bf16* src, __bf16* dst,
                                        size_t rowstride, int wave, int lane) {
#pragma unroll
  for (int i = 0; i < 2; ++i) {
    const int chunk = wave * 2 + i;            // 16 chunks of 16 rows
    const int row = chunk * 16 + (lane >> 2);
    const int gg = (lane & 3) ^ ((row >> 1) & 3);   // pre-swizzled source
    gload_lds16(src + (size_t)row * rowstride + (gg << 3), dst + chunk * 512);
  }
}

template <int MH>
__device__ __forceinline__ void mfma16(f32x4 (&acc)[8][4], const bf16x8 (&a)[4],
                                       const bf16x8 (&b)[4]) {
#pragma unroll
  for (int mi = 0; mi < 4; ++mi)
#pragma unroll
    for (int nj = 0; nj < 4; ++nj)
      acc[MH * 4 + mi][nj] = __builtin_amdgcn_mfma_f32_16x16x32_bf16(
          a[mi], b[nj], acc[MH * 4 + mi][nj], 0, 0, 0);
}

#define PHASE_MID()                       \
  __builtin_amdgcn_sched_barrier(0);      \
  __builtin_amdgcn_s_barrier();           \
  __builtin_amdgcn_s_setprio(1)

#define PHASE_END()                       \
  __builtin_amdgcn_s_setprio(0);          \
  __builtin_amdgcn_sched_barrier(0);      \
  __builtin_amdgcn_s_barrier()

// ---------------------------------------------------------------------------
// One 256x256 output tile, NT: C[m,n] += sum_k A[m,k]*B[n,k], K mult of 128.
// 8-phase double-buffered schedule, counted vmcnt(6) at phases 4/8 only.
// Safe to call back-to-back: after the last phase-8 barrier LDS is quiescent
// (all ds_reads consumed pre-barrier), so the next call's prologue may write
// LDS immediately; FIFO vmcnt makes its waits also cover the prior epilogue's
// store drain (max instead of sum). All barriers are block-uniform.
// ---------------------------------------------------------------------------
template <bool OUTBF16>
__device__ __forceinline__ void tile_gemm(
    const __bf16* __restrict__ Aa, const __bf16* __restrict__ Ba,
    void* __restrict__ Cp, size_t cbase, int N, int K, float scale,
    __bf16* lds, int wave, int lane, int wm, int wn, int fm, int gq) {
  __bf16* const As_ = lds;
  __bf16* const Bs_ = lds + 32768;
#define AREG(p, h) (As_ + (p) * 16384 + (h) * 8192)
#define BREG(p, h) (Bs_ + (p) * 16384 + (h) * 8192)

  f32x4 acc[8][4] = {};
  bf16x8 a[4], b[4];

  // ---- prologue: tile0 fully + 3 halves of tile1 ----
  stage16(Ba + 0,  BREG(0, 0), K, wave, lane);
  stage16(Aa + 0,  AREG(0, 0), K, wave, lane);
  stage16(Ba + 32, BREG(0, 1), K, wave, lane);
  stage16(Aa + 32, AREG(0, 1), K, wave, lane);
  asm volatile("s_waitcnt vmcnt(4)" ::: "memory");
  stage16(Ba + 64, BREG(1, 0), K, wave, lane);
  stage16(Aa + 64, AREG(1, 0), K, wave, lane);
  stage16(Ba + 96, BREG(1, 1), K, wave, lane);
  asm volatile("s_waitcnt vmcnt(6)" ::: "memory");
  __builtin_amdgcn_s_barrier();

  const int niter = K >> 7;   // 2 K-tiles (BK=64) per iteration
  for (int it = 0; it < niter; ++it) {
    const int kt = it << 7;
    const bool s2 = (kt + 128) < K;   // tiles t+2 / t+3 exist (block-uniform)

    // ---- phase 1: buf0 (mh0,kh0); stage (t+1).A-kh1 ----
    ldfrag4(a, AREG(0, 0), wm, fm, gq);
    ldfrag4(b, BREG(0, 0), wn, fm, gq);
    stage16(Aa + kt + 96, AREG(1, 1), K, wave, lane);
    PHASE_MID();
    mfma16<0>(acc, a, b);
    PHASE_END();

    // ---- phase 2: (mh1,kh0); stage (t+2).B-kh0 ----
    ldfrag4(a, AREG(0, 0), wm + 64, fm, gq);
    if (s2) stage16(Ba + kt + 128, BREG(0, 0), K, wave, lane);
    PHASE_MID();
    mfma16<1>(acc, a, b);
    PHASE_END();

    // ---- phase 3: (mh0,kh1); stage (t+2).A-kh0 ----
    ldfrag4(a, AREG(0, 1), wm, fm, gq);
    ldfrag4(b, BREG(0, 1), wn, fm, gq);
    if (s2) stage16(Aa + kt + 128, AREG(0, 0), K, wave, lane);
    PHASE_MID();
    mfma16<0>(acc, a, b);
    PHASE_END();

    // ---- phase 4: (mh1,kh1); stage (t+2).B-kh1; counted vmcnt ----
    ldfrag4(a, AREG(0, 1), wm + 64, fm, gq);
    if (s2) stage16(Ba + kt + 160, BREG(0, 1), K, wave, lane);
    PHASE_MID();
    mfma16<1>(acc, a, b);
    __builtin_amdgcn_s_setprio(0);
    __builtin_amdgcn_sched_barrier(0);
    if (s2) { asm volatile("s_waitcnt vmcnt(6)" ::: "memory"); }
    else    { asm volatile("s_waitcnt vmcnt(0)" ::: "memory"); }
    __builtin_amdgcn_s_barrier();

    // ---- phase 5: buf1 (mh0,kh0); stage (t+2).A-kh1 ----
    ldfrag4(a, AREG(1, 0), wm, fm, gq);
    ldfrag4(b, BREG(1, 0), wn, fm, gq);
    if (s2) stage16(Aa + kt + 160, AREG(0, 1), K, wave, lane);
    PHASE_MID();
    mfma16<0>(acc, a, b);
    PHASE_END();

    // ---- phase 6: (mh1,kh0); stage (t+3).B-kh0 ----
    ldfrag4(a, AREG(1, 0), wm + 64, fm, gq);
    if (s2) stage16(Ba + kt + 192, BREG(1, 0), K, wave, lane);
    PHASE_MID();
    mfma16<1>(acc, a, b);
    PHASE_END();

    // ---- phase 7: (mh0,kh1); stage (t+3).A-kh0 ----
    ldfrag4(a, AREG(1, 1), wm, fm, gq);
    ldfrag4(b, BREG(1, 1), wn, fm, gq);
    if (s2) stage16(Aa + kt + 192, AREG(1, 0), K, wave, lane);
    PHASE_MID();
    mfma16<0>(acc, a, b);
    PHASE_END();

    // ---- phase 8: (mh1,kh1); stage (t+3).B-kh1; counted vmcnt ----
    ldfrag4(a, AREG(1, 1), wm + 64, fm, gq);
    if (s2) stage16(Ba + kt + 224, BREG(1, 1), K, wave, lane);
    PHASE_MID();
    mfma16<1>(acc, a, b);
    __builtin_amdgcn_s_setprio(0);
    __builtin_amdgcn_sched_barrier(0);
    if (s2) { asm volatile("s_waitcnt vmcnt(6)" ::: "memory"); }
    __builtin_amdgcn_s_barrier();
  }

  // ---- epilogue: C/D layout col=lane&15, row=(lane>>4)*4+reg ----
  const int col   = lane & 15;
  const int rquad = (lane >> 4) * 4;
#pragma unroll
  for (int mi = 0; mi < 8; ++mi) {
#pragma unroll
    for (int r = 0; r < 4; ++r) {
      const size_t roff = (size_t)(wm + mi * 16 + rquad + r) * (size_t)N;
#pragma unroll
      for (int nj = 0; nj < 4; ++nj) {
        const size_t cidx = cbase + roff + wn + nj * 16 + col;
        if constexpr (OUTBF16) {
          ((__bf16*)Cp)[cidx] = (__bf16)acc[mi][nj][r];
        } else {
          ((float*)Cp)[cidx] = acc[mi][nj][r] * scale;
        }
      }
    }
  }
#undef AREG
#undef BREG
}

// ---------------------------------------------------------------------------
// proj_all: 256 blocks, 3 chained tiles each.
//   tile0: WQ  = rnnb @ Wt   (M=16384,N=1024,K=1024)  by=x*8+(s>>2), bx=s&3
//   tile1: WK  = Ltb  @ k0t  (same geometry)
//   tile2: WVt[b][e][k] = k1t[e,:] . Ltb[b][k,:]  (M=1024,N=2048,K=1024)
// ---------------------------------------------------------------------------
__global__ __launch_bounds__(512, 2)
void proj_all(const __bf16* __restrict__ rnnb, const __bf16* __restrict__ Ltb,
              const __bf16* __restrict__ Wt, const __bf16* __restrict__ k0t,
              const __bf16* __restrict__ k1t, __bf16* __restrict__ WQ,
              __bf16* __restrict__ WK, __bf16* __restrict__ WVt) {
  __shared__ __bf16 lds[65536];
  const int tid = threadIdx.x, wave = tid >> 6, lane = tid & 63;
  const int wm = (wave >> 2) * 128, wn = (wave & 3) * 64;
  const int fm = lane & 15, gq = lane >> 4;
  const int d = blockIdx.x, x = d & 7, s = d >> 3;

  {  // projections: 64 by-panels x 4 bx; XCD x owns by in [8x, 8x+8)
    const int bx = s & 3, by = x * 8 + (s >> 2);
    const size_t ao = (size_t)by * 256 * 1024;
    const size_t bo = (size_t)bx * 256 * 1024;
    const size_t cb = (size_t)by * 256 * 1024 + (size_t)bx * 256;
    tile_gemm<true>(rnnb + ao, Wt + bo, WQ, cb, 1024, 1024, 1.0f,
                    lds, wave, lane, wm, wn, fm, gq);
    tile_gemm<true>(Ltb + ao, k0t + bo, WK, cb, 1024, 1024, 1.0f,
                    lds, wave, lane, wm, wn, fm, gq);
  }
  {  // WV: batch x on XCD x; by = e-tile (0..3), bx = k-tile (0..7)
    const int by = s >> 3, bx = s & 7;
    tile_gemm<true>(k1t + (size_t)by * 256 * 1024,
                    Ltb + (size_t)x * 2048 * 1024 + (size_t)bx * 256 * 1024,
                    WVt,
                    (size_t)x * 1024 * 2048 + (size_t)by * 256 * 2048 +
                        (size_t)bx * 256,
                    2048, 1024, 1.0f, lds, wave, lane, wm, wn, fm, gq);
  }
}

// ---------------------------------------------------------------------------
// qk2: 256 blocks, 2 chained tiles (same B-panel, L2-hot on 2nd tile).
// wts[b][q][k] = 0.125 * WQ[b][q,:] . WK[b][k,:]
// ---------------------------------------------------------------------------
__global__ __launch_bounds__(512, 2)
void qk2(const __bf16* __restrict__ WQ, const __bf16* __restrict__ WK,
         float* __restrict__ wts) {
  __shared__ __bf16 lds[65536];
  const int tid = threadIdx.x, wave = tid >> 6, lane = tid & 63;
  const int wm = (wave >> 2) * 128, wn = (wave & 3) * 64;
  const int fm = lane & 15, gq = lane >> 4;
  const int d = blockIdx.x, x = d & 7, s = d >> 3;
  const int by = s >> 3, bx = s & 7;   // by 0..3 (then +4), bx 0..7

  const __bf16* Qb = WQ + (size_t)x * 2048 * 1024;
  const __bf16* Kb = WK + (size_t)x * 2048 * 1024 + (size_t)bx * 256 * 1024;
  const size_t cb0 = (size_t)x * 2048 * 2048 + (size_t)bx * 256;

  tile_gemm<false>(Qb + (size_t)by * 256 * 1024, Kb, wts,
                   cb0 + (size_t)by * 256 * 2048, 2048, 1024, 0.125f,
                   lds, wave, lane, wm, wn, fm, gq);
  tile_gemm<false>(Qb + (size_t)(by + 4) * 256 * 1024, Kb, wts,
                   cb0 + (size_t)(by + 4) * 256 * 2048, 2048, 1024, 0.125f,
                   lds, wave, lane, wm, wn, fm, gq);
}

// ---------------------------------------------------------------------------
// pv1: 256 blocks, 1 tile. ctx[b][q][e] = Pb[b][q,:] . WVt[b][e,:]
// ---------------------------------------------------------------------------
__global__ __launch_bounds__(512, 2)
void pv1(const __bf16* __restrict__ Pb, const __bf16* __restrict__ WVt,
         float* __restrict__ ctx) {
  __shared__ __bf16 lds[65536];
  const int tid = threadIdx.x, wave = tid >> 6, lane = tid & 63;
  const int wm = (wave >> 2) * 128, wn = (wave & 3) * 64;
  const int fm = lane & 15, gq = lane >> 4;
  const int d = blockIdx.x, x = d & 7, s = d >> 3;
  const int by = s >> 2, bx = s & 3;   // by 0..7 (q-tile), bx 0..3 (e-tile)

  tile_gemm<false>(Pb + (size_t)x * 2048 * 2048 + (size_t)by * 256 * 2048,
                   WVt + (size_t)x * 1024 * 2048 + (size_t)bx * 256 * 2048,
                   ctx,
                   (size_t)x * 2048 * 1024 + (size_t)by * 256 * 1024 +
                       (size_t)bx * 256,
                   1024, 2048, 1.0f, lds, wave, lane, wm, wn, fm, gq);
}

// ---------------------------------------------------------------------------
// cvt+transpose 1024x1024 f32 -> bf16 (out[n,d] = in[d,n]); z selects matrix
// ---------------------------------------------------------------------------
__global__ __launch_bounds__(256)
void cvt_transpose(const float* __restrict__ s0, const float* __restrict__ s1,
                   const float* __restrict__ s2, __bf16* __restrict__ d0,
                   __bf16* __restrict__ d1, __bf16* __restrict__ d2) {
  const float* s = blockIdx.z == 0 ? s0 : (blockIdx.z == 1 ? s1 : s2);
  __bf16* d      = blockIdx.z == 0 ? d0 : (blockIdx.z == 1 ? d1 : d2);
  __shared__ float tile[32][33];
  const int x  = blockIdx.x * 32 + threadIdx.x;
  const int y0 = blockIdx.y * 32;
  for (int j = threadIdx.y; j < 32; j += 8)
    tile[j][threadIdx.x] = s[(size_t)(y0 + j) * 1024 + x];
  __syncthreads();
  const int x2 = y0 + threadIdx.x;
  const int y2 = blockIdx.x * 32;
  for (int j = threadIdx.y; j < 32; j += 8)
    d[(size_t)(y2 + j) * 1024 + x2] = (__bf16)tile[threadIdx.x][j];
}

// ---------------------------------------------------------------------------
// elementwise f32 -> bf16, Lt and rnn_ht
// ---------------------------------------------------------------------------
__global__ __launch_bounds__(256)
void cvt_bf16(const float* __restrict__ s0, __bf16* __restrict__ d0,
              const float* __restrict__ s1, __bf16* __restrict__ d1) {
  const float* s = blockIdx.z ? s1 : s0;
  __bf16* d      = blockIdx.z ? d1 : d0;
  const size_t i = ((size_t)blockIdx.x * 256 + threadIdx.x) * 4;
  float4 f = *(const float4*)(s + i);
  bf16x4 h = {(__bf16)f.x, (__bf16)f.y, (__bf16)f.z, (__bf16)f.w};
  *(bf16x4*)(d + i) = h;
}

// ---------------------------------------------------------------------------
// row softmax in place: 16384 rows x 2048 f32, one block per row.
// Also emits a bf16 copy of the row (PV GEMM A-operand).
// ---------------------------------------------------------------------------
__global__ __launch_bounds__(256)
void softmax_rows(float* __restrict__ Wt, __bf16* __restrict__ Pb) {
  const int t = threadIdx.x;
  float* p = Wt + (size_t)blockIdx.x * 2048;
  float4 a = ((float4*)p)[t];
  float4 b = ((float4*)p)[t + 256];

  float m = fmaxf(fmaxf(fmaxf(a.x, a.y), fmaxf(a.z, a.w)),
                  fmaxf(fmaxf(b.x, b.y), fmaxf(b.z, b.w)));
#pragma unroll
  for (int off = 32; off > 0; off >>= 1) m = fmaxf(m, __shfl_xor(m, off));
  __shared__ float red[8];
  if ((t & 63) == 0) red[t >> 6] = m;
  __syncthreads();
  m = fmaxf(fmaxf(red[0], red[1]), fmaxf(red[2], red[3]));

  a.x = __expf(a.x - m); a.y = __expf(a.y - m);
  a.z = __expf(a.z - m); a.w = __expf(a.w - m);
  b.x = __expf(b.x - m); b.y = __expf(b.y - m);
  b.z = __expf(b.z - m); b.w = __expf(b.w - m);
  float s = a.x + a.y + a.z + a.w + b.x + b.y + b.z + b.w;
#pragma unroll
  for (int off = 32; off > 0; off >>= 1) s += __shfl_xor(s, off);
  if ((t & 63) == 0) red[4 + (t >> 6)] = s;
  __syncthreads();
  s = red[4] + red[5] + red[6] + red[7];

  const float inv = 1.0f / s;
  a.x *= inv; a.y *= inv; a.z *= inv; a.w *= inv;
  b.x *= inv; b.y *= inv; b.z *= inv; b.w *= inv;
  ((float4*)p)[t] = a;
  ((float4*)p)[t + 256] = b;

  __bf16* pb = Pb + (size_t)blockIdx.x * 2048;
  bf16x4 ha = {(__bf16)a.x, (__bf16)a.y, (__bf16)a.z, (__bf16)a.w};
  bf16x4 hb = {(__bf16)b.x, (__bf16)b.y, (__bf16)b.z, (__bf16)b.w};
  *(bf16x4*)(pb + (size_t)t * 4) = ha;
  *(bf16x4*)(pb + (size_t)(t + 256) * 4) = hb;
}

// ---------------------------------------------------------------------------
extern "C" void kernel_launch(void* const* d_in, const int* in_sizes, int n_in,
                              void* d_out, int out_size, void* d_ws,
                              size_t ws_size, hipStream_t stream) {
  const float* Lt  = (const float*)d_in[0];  // [8,2048,1024]
  const float* rnn = (const float*)d_in[1];  // [8,2048,1024]
  const float* ker = (const float*)d_in[2];  // [2,1024,1024]
  const float* W   = (const float*)d_in[3];  // [1024,1024]

  float* ctx = (float*)d_out;                // [8,2048,1024]
  float* wts = ctx + (size_t)16777216;       // [8,2048,2048]

  __bf16* ws   = (__bf16*)d_ws;
  __bf16* Wt   = ws;                         // [1024,1024]  (n,d)   2 MiB
  __bf16* k0t  = Wt + (1u << 20);            // [1024,1024]          2 MiB
  __bf16* k1t  = k0t + (1u << 20);           // [1024,1024]          2 MiB
  __bf16* WQ   = k1t + (1u << 20);           // [8*2048,1024]       32 MiB
  __bf16* WK   = WQ + (16u << 20);           // [8*2048,1024]       32 MiB
  __bf16* WVt  = WK + (16u << 20);           // [8][1024][2048]     32 MiB
  __bf16* Ltb  = WVt + (16u << 20);          // [8,2048,1024] bf16  32 MiB
  __bf16* rnnb = Ltb + (16u << 20);          // [8,2048,1024] bf16  32 MiB
  __bf16* Pb = Ltb;  // P overlaps Ltb+rnnb (dead after proj_all/qk2) 64 MiB

  // 1) transpose + cvt the three weight matrices
  cvt_transpose<<<dim3(32, 32, 3), dim3(32, 8), 0, stream>>>(
      W, ker, ker + (1u << 20), Wt, k0t, k1t);

  // 1b) cvt Lt and rnn_ht to bf16
  cvt_bf16<<<dim3(16384, 1, 2), 256, 0, stream>>>(Lt, Ltb, rnn, rnnb);

  // 2) WQ, WK, WVt in one launch (3 chained tiles per block)
  proj_all<<<256, 512, 0, stream>>>(rnnb, Ltb, Wt, k0t, k1t, WQ, WK, WVt);

  // 3) QK logits, *0.125 (2 chained tiles per block)
  qk2<<<256, 512, 0, stream>>>(WQ, WK, wts);

  // 4) softmax rows in place (+ bf16 copy for PV)
  softmax_rows<<<16384, 256, 0, stream>>>(wts, Pb);

  // 5) ctx[b,q,e] = sum_k P[b,q,k] * WVt[b,e,k]
  pv1<<<256, 512, 0, stream>>>(Pb, WVt, ctx);
}